// Round 9
// baseline (204.708 us; speedup 1.0000x reference)
//
#include <hip/hip_runtime.h>
#include <hip/hip_bf16.h>

// GATLayer: x[8,1024,128], e[8,1024,1024], H=8 dh=16, CLIP=10, FF=512.
// R7: attn split 4x across blocks (grid 1024x512, partial-sum f32 outputs,
// permlane32_swap pack, LDS=0); normalize folded into fused_ffn step 1.

typedef __attribute__((ext_vector_type(4)))  float  f32x4;
typedef __attribute__((ext_vector_type(16))) float  f32x16;
typedef __attribute__((ext_vector_type(8)))  __bf16 bf8v;

#define DEV static __device__ __forceinline__

DEV ushort f2bf(float f) {
  __hip_bfloat16 h = __float2bfloat16(f);
  return __builtin_bit_cast(ushort, h);
}

DEV uint cvtpk(float lo, float hi) {
  uint r;
  asm("v_cvt_pk_bf16_f32 %0, %1, %2" : "=v"(r) : "v"(lo), "v"(hi));
  return r;
}

DEV f32x16 zero16() {
  f32x16 z;
#pragma unroll
  for (int i = 0; i < 16; ++i) z[i] = 0.0f;
  return z;
}

union PU {
  uint u[4];
  bf8v v;
};

// ---------------- kernel 0: prep (bf16 convert + weight transposes) -------
DEV void tr_w(const float* __restrict__ S, ushort* __restrict__ D,
              int N, int K, int idx) {
  // D[n][k] = bf16(S[k][n]); one thread handles 4 consecutive k.
  int kq = K >> 2;
  int n = idx / kq;
  int k = (idx - n * kq) << 2;
  ushort4 o;
  o.x = f2bf(S[(size_t)(k + 0) * N + n]);
  o.y = f2bf(S[(size_t)(k + 1) * N + n]);
  o.z = f2bf(S[(size_t)(k + 2) * N + n]);
  o.w = f2bf(S[(size_t)(k + 3) * N + n]);
  *(ushort4*)&D[(size_t)n * K + k] = o;
}

__global__ __launch_bounds__(256) void prep_kernel(
    const float* __restrict__ x,  const float* __restrict__ Wq,
    const float* __restrict__ Wk, const float* __restrict__ Wv,
    const float* __restrict__ Wo, const float* __restrict__ W1,
    const float* __restrict__ W2,
    ushort* __restrict__ xb,  ushort* __restrict__ Wqt,
    ushort* __restrict__ Wkt, ushort* __restrict__ Wvt,
    ushort* __restrict__ Wot, ushort* __restrict__ W1t,
    ushort* __restrict__ W2t) {
  const int bid = blockIdx.x, tid = threadIdx.x;
  if (bid < 1024) {
    // xb: 8192x128 f32 -> bf16, 4 elems/thread
    int base = (bid * 256 + tid) * 4;
    f32x4 v = *(const f32x4*)(x + base);
    ushort4 o = make_ushort4(f2bf(v.x), f2bf(v.y), f2bf(v.z), f2bf(v.w));
    *(ushort4*)&xb[base] = o;
  } else {
    int gi = (bid - 1024) * 256 + tid;
    if      (gi < 4096)  tr_w(Wq, Wqt, 128, 128, gi);
    else if (gi < 8192)  tr_w(Wk, Wkt, 128, 128, gi - 4096);
    else if (gi < 12288) tr_w(Wv, Wvt, 128, 128, gi - 8192);
    else if (gi < 16384) tr_w(Wo, Wot, 128, 128, gi - 12288);
    else if (gi < 32768) tr_w(W1, W1t, 512, 128, gi - 16384);
    else                 tr_w(W2, W2t, 128, 512, gi - 32768);
  }
}

// ---------------- no-LDS 16x16x32 GEMM wave-tile --------------------------
// A bf16 [M][K] row-major, Bt bf16 [N][K] row-major (B transposed).
// A-frag: row=lane&15, k=8*(lane>>4)+j. C: col=lane&15, row=(lane>>4)*4+i.
template <int K>
DEV f32x4 gemm16(const ushort* __restrict__ A, const ushort* __restrict__ Bt,
                 int m0, int n0, int lane) {
  const int r = lane & 15, g = lane >> 4;
  const ushort* pa = A + (size_t)(m0 + r) * K + g * 8;
  const ushort* pb = Bt + (size_t)(n0 + r) * K + g * 8;
  f32x4 acc = {0.0f, 0.0f, 0.0f, 0.0f};
#pragma unroll
  for (int k0 = 0; k0 < K; k0 += 32) {
    bf8v a = *(const bf8v*)(pa + k0);
    bf8v b = *(const bf8v*)(pb + k0);
    acc = __builtin_amdgcn_mfma_f32_16x16x32_bf16(a, b, acc, 0, 0, 0);
  }
  return acc;
}

// Same, but A-fragment comes from an LDS tile (row stride LDA ushorts).
template <int K, int LDA>
DEV f32x4 gemm16_a_lds(const ushort* As, const ushort* __restrict__ Bt,
                       int n0, int lane) {
  const int r = lane & 15, g = lane >> 4;
  const ushort* pa = As + r * LDA + g * 8;
  const ushort* pb = Bt + (size_t)(n0 + r) * K + g * 8;
  f32x4 acc = {0.0f, 0.0f, 0.0f, 0.0f};
#pragma unroll
  for (int k0 = 0; k0 < K; k0 += 32) {
    bf8v a = *(const bf8v*)(pa + k0);
    bf8v b = *(const bf8v*)(pb + k0);
    acc = __builtin_amdgcn_mfma_f32_16x16x32_bf16(a, b, acc, 0, 0, 0);
  }
  return acc;
}

// ---------------- kernel 1: QKV projection --------------------------------
// 3 projs x 512 mt x 8 nt = 12288 wave-tiles; 4 waves/block -> 3072 blocks.
// Writes Q,K [B,H,N,16] bf16; V transposed [B,H,16,N] bf16.
__global__ __launch_bounds__(256) void proj_kernel(
    const ushort* __restrict__ xb,  const ushort* __restrict__ Wqt,
    const ushort* __restrict__ Wkt, const ushort* __restrict__ Wvt,
    ushort* __restrict__ Qb, ushort* __restrict__ Kb, ushort* __restrict__ Vt) {
  const int w = blockIdx.x * 4 + (threadIdx.x >> 6);
  const int lane = threadIdx.x & 63;
  const int p = w >> 12;            // which projection
  const int t = w & 4095;
  const int mt = t >> 3, nt = t & 7;
  const ushort* Wt = p == 0 ? Wqt : (p == 1 ? Wkt : Wvt);
  f32x4 acc = gemm16<128>(xb, Wt, mt * 16, nt * 16, lane);
  const int g = lane >> 4, col = lane & 15;
  const int h = nt, d = col;        // 16-wide n-tiles align with heads
  if (p < 2) {
    ushort* dst = p ? Kb : Qb;
#pragma unroll
    for (int i = 0; i < 4; ++i) {
      int m = mt * 16 + g * 4 + i;
      int bb = m >> 10, ns = m & 1023;
      dst[((size_t)(bb * 8 + h) * 1024 + ns) * 16 + d] = f2bf(acc[i]);
    }
  } else {
    int m0 = mt * 16 + g * 4;
    int bb = m0 >> 10, ns = m0 & 1023;
    ushort4 pk = make_ushort4(f2bf(acc[0]), f2bf(acc[1]),
                              f2bf(acc[2]), f2bf(acc[3]));
    *(ushort4*)&Vt[((size_t)(bb * 8 + h) * 16 + d) * 1024 + ns] = pk;
  }
}

// ---------------- kernel 2: fused attention -------------------------------
// grid = B*32*4 = 1024 blocks: (b, 32-q tile, m-quarter). 512 thr = 8 waves
// = 8 heads, each wave covers 256 m's. Outputs UNNORMALIZED f32 partial
// numerators Pp[mh] and partial denominators Dp[mh]; consumer normalizes.
// Swapped QK^T (32x32x16): lane owns q=lane&31; tanh clip -> fixed-max
// softmax (no running max). Pack via v_permlane32_swap_b32.
__global__ __launch_bounds__(512, 6) void attn_kernel(
    const ushort* __restrict__ Qb, const ushort* __restrict__ Kb,
    const ushort* __restrict__ Vt, const float* __restrict__ e,
    float* __restrict__ Pp, float* __restrict__ Dp) {
  const int mh = blockIdx.x & 3, bq = blockIdx.x >> 2;
  const int b = bq >> 5, qt = bq & 31;
  const int h = threadIdx.x >> 6, lane = threadIdx.x & 63;
  const int lq = lane & 31, hi = lane >> 5;
  const int q0 = qt * 32;
  const ushort* Qh = Qb + (size_t)(b * 8 + h) * (1024 * 16);
  const ushort* Kh = Kb + (size_t)(b * 8 + h) * (1024 * 16);
  const ushort* Vh = Vt + (size_t)(b * 8 + h) * (16 * 1024);
  const float* erow = e + ((size_t)b * 1024 + q0 + lq) * 1024;

  const bf8v qf = *(const bf8v*)(Qh + (q0 + lq) * 16 + hi * 8);
  f32x16 acc = zero16();
  float ssum = 0.0f;
  const float C2 = 2.8853900817779268f;    // 2*log2(e)
  const float C1 = -28.853900817779268f;   // -20*log2(e)

#pragma unroll 2
  for (int mt = 0; mt < 8; ++mt) {
    const int mbase = mh * 256 + mt * 32;
    bf8v kf = *(const bf8v*)(Kh + (mbase + lq) * 16 + hi * 8);
    f32x16 s = __builtin_amdgcn_mfma_f32_32x32x16_bf16(kf, qf, zero16(), 0, 0, 0);
    f32x4 ev[4];
#pragma unroll
    for (int g = 0; g < 4; ++g)
      ev[g] = *(const f32x4*)(erow + mbase + 4 * hi + 8 * g);
    float p[16];
#pragma unroll
    for (int r = 0; r < 16; ++r) {
      float y = s[r] * 0.25f + ev[r >> 2][r & 3];
      // p = exp(10*tanh(y) - 10) = exp2(C1 / (1 + exp2(C2*y)))
      float z = __builtin_amdgcn_exp2f(C2 * y);
      float pp = __builtin_amdgcn_exp2f(C1 * __builtin_amdgcn_rcpf(1.0f + z));
      p[r] = pp;
      ssum += pp;
    }
    uint w[8];
#pragma unroll
    for (int j = 0; j < 8; ++j) w[j] = cvtpk(p[2 * j], p[2 * j + 1]);
    // A-frag assembly: swap(wA,wB) leaves wA = own-lo/partner-lo-of-wB and
    // wB = partner-hi-of-wA/own-hi, exactly the (hi?:) selects of R4.
    asm("v_permlane32_swap_b32 %0, %1" : "+v"(w[0]), "+v"(w[2]));
    asm("v_permlane32_swap_b32 %0, %1" : "+v"(w[1]), "+v"(w[3]));
    asm("v_permlane32_swap_b32 %0, %1" : "+v"(w[4]), "+v"(w[6]));
    asm("v_permlane32_swap_b32 %0, %1" : "+v"(w[5]), "+v"(w[7]));
    PU a0, a1;
    a0.u[0] = w[0]; a0.u[1] = w[1]; a0.u[2] = w[2]; a0.u[3] = w[3];
    a1.u[0] = w[4]; a1.u[1] = w[5]; a1.u[2] = w[6]; a1.u[3] = w[7];
    PU v0, v1;
#pragma unroll
    for (int j = 0; j < 4; ++j) { v0.u[j] = 0; v1.u[j] = 0; }
    if (lq < 16) {
      v0.v = *(const bf8v*)(Vh + lq * 1024 + mbase + hi * 8);
      v1.v = *(const bf8v*)(Vh + lq * 1024 + mbase + 16 + hi * 8);
    }
    acc = __builtin_amdgcn_mfma_f32_32x32x16_bf16(a0.v, v0.v, acc, 0, 0, 0);
    acc = __builtin_amdgcn_mfma_f32_32x32x16_bf16(a1.v, v1.v, acc, 0, 0, 0);
  }
  // partial denominator for q = lq (this lane's 16 m's + partner's 16)
  float tot = ssum + __shfl_xor(ssum, 32);
  if (hi == 0)
    Dp[((size_t)mh * 64 + b * 8 + h) * 1024 + q0 + lq] = tot;
  // partial numerator: acc reg r -> row q_r, col d = lq (d<16 valid)
  float* Pq = Pp + (size_t)mh * (8192 * 128);
#pragma unroll
  for (int r = 0; r < 16; ++r) {
    int qr = (r & 3) + 8 * (r >> 2) + 4 * hi;
    if (lq < 16)
      Pq[((size_t)(b * 1024) + q0 + qr) * 128 + h * 16 + lq] = acc[r];
  }
}

// ---------------- kernel 3: normalize + Wo+res1 -> FFN1 -> FFN2+res2 ------
// grid = 512 blocks (one per 16-row m-tile), 512 thr = 8 waves.
// Step 1 sums the 4 attention partials, normalizes, converts to bf16
// fragments on the fly, then GEMMs with Wo. X1/H tiles live in LDS.
__global__ __launch_bounds__(512) void fused_ffn_kernel(
    const float* __restrict__ Pp, const float* __restrict__ Dp,
    const ushort* __restrict__ Wot,
    const float* __restrict__ x, const float* __restrict__ alpha1,
    const ushort* __restrict__ W1t, const float* __restrict__ b1,
    const ushort* __restrict__ W2t, const float* __restrict__ b2,
    const float* __restrict__ alpha2, float* __restrict__ out) {
  __shared__ float  X1f[16][132];
  __shared__ ushort X1b[16][136];
  __shared__ ushort Hs[16][520];
  const int mtile = blockIdx.x;
  const int w = threadIdx.x >> 6, lane = threadIdx.x & 63;
  const int g = lane >> 4, col = lane & 15;
  const float a1 = *alpha1, a2 = *alpha2;

  // step 1: X1 = x + a1 * (norm(P) @ Wo); wave w owns cols w*16..w*16+15
  {
    const int r = lane & 15;
    const int m = mtile * 16 + r;        // A-row this lane supplies
    const int bb = m >> 10, ns = m & 1023;
    f32x4 acc4 = {0.0f, 0.0f, 0.0f, 0.0f};
#pragma unroll
    for (int k0 = 0; k0 < 128; k0 += 32) {
      const int k = k0 + g * 8;          // AO column base (within one head)
      const int hh = k >> 4;
      float den = 0.0f;
#pragma unroll
      for (int q = 0; q < 4; ++q)
        den += Dp[((size_t)q * 64 + bb * 8 + hh) * 1024 + ns];
      const float rd = __builtin_amdgcn_rcpf(den);
      f32x4 s0 = {0.0f, 0.0f, 0.0f, 0.0f}, s1 = {0.0f, 0.0f, 0.0f, 0.0f};
#pragma unroll
      for (int q = 0; q < 4; ++q) {
        const float* P = Pp + (size_t)q * (8192 * 128) + (size_t)m * 128 + k;
        s0 += *(const f32x4*)P;
        s1 += *(const f32x4*)(P + 4);
      }
      PU a;
      a.u[0] = cvtpk(s0.x * rd, s0.y * rd);
      a.u[1] = cvtpk(s0.z * rd, s0.w * rd);
      a.u[2] = cvtpk(s1.x * rd, s1.y * rd);
      a.u[3] = cvtpk(s1.z * rd, s1.w * rd);
      bf8v bfr = *(const bf8v*)(Wot + (size_t)(w * 16 + r) * 128 + g * 8 + k0);
      acc4 = __builtin_amdgcn_mfma_f32_16x16x32_bf16(a.v, bfr, acc4, 0, 0, 0);
    }
    int n = w * 16 + col;
#pragma unroll
    for (int i = 0; i < 4; ++i) {
      int row = g * 4 + i;
      float v = x[(size_t)(mtile * 16 + row) * 128 + n] + a1 * acc4[i];
      X1f[row][n] = v;
      X1b[row][n] = f2bf(v);
    }
  }
  __syncthreads();

  // step 2: H = relu(X1b @ W1 + b1); wave w owns cols w*64..w*64+63
#pragma unroll
  for (int j = 0; j < 4; ++j) {
    int n0 = w * 64 + j * 16;
    f32x4 acc = gemm16_a_lds<128, 136>(&X1b[0][0], W1t, n0, lane);
    int n = n0 + col;
    float bias = b1[n];
#pragma unroll
    for (int i = 0; i < 4; ++i) {
      int row = g * 4 + i;
      Hs[row][n] = f2bf(fmaxf(acc[i] + bias, 0.0f));
    }
  }
  __syncthreads();

  // step 3: out = X1 + a2 * (H @ W2 + b2); wave w owns cols w*16..w*16+15
  {
    f32x4 acc = gemm16_a_lds<512, 520>(&Hs[0][0], W2t, w * 16, lane);
    int n = w * 16 + col;
    float bias = b2[n];
#pragma unroll
    for (int i = 0; i < 4; ++i) {
      int row = g * 4 + i;
      out[(size_t)(mtile * 16 + row) * 128 + n] =
          X1f[row][n] + a2 * (acc[i] + bias);
    }
  }
}

// ---------------- launcher -------------------------------------------------
extern "C" void kernel_launch(void* const* d_in, const int* in_sizes, int n_in,
                              void* d_out, int out_size, void* d_ws, size_t ws_size,
                              hipStream_t stream) {
  (void)in_sizes; (void)n_in; (void)out_size; (void)ws_size;
  const float* x  = (const float*)d_in[0];
  const float* e  = (const float*)d_in[1];
  const float* Wq = (const float*)d_in[2];
  const float* Wk = (const float*)d_in[3];
  const float* Wv = (const float*)d_in[4];
  const float* Wo = (const float*)d_in[5];
  const float* W1 = (const float*)d_in[6];
  const float* b1 = (const float*)d_in[7];
  const float* W2 = (const float*)d_in[8];
  const float* b2 = (const float*)d_in[9];
  const float* a1 = (const float*)d_in[10];
  const float* a2 = (const float*)d_in[11];
  float* out = (float*)d_out;

  char* ws = (char*)d_ws;
  ushort* Qb  = (ushort*)(ws);                      // 2 MB [B,H,N,16]
  ushort* Kb  = (ushort*)(ws + (2ull << 20));       // 2 MB
  ushort* Vt  = (ushort*)(ws + (4ull << 20));       // 2 MB [B,H,16,N]
  ushort* xb  = (ushort*)(ws + (6ull << 20));       // 2 MB [8192,128]
  ushort* Wqt = (ushort*)(ws + (8ull << 20));               // 32 KB each
  ushort* Wkt = (ushort*)(ws + (8ull << 20) + (32u << 10));
  ushort* Wvt = (ushort*)(ws + (8ull << 20) + (64u << 10));
  ushort* Wot = (ushort*)(ws + (8ull << 20) + (96u << 10));
  ushort* W1t = (ushort*)(ws + (8ull << 20) + (128u << 10)); // 128 KB
  ushort* W2t = (ushort*)(ws + (8ull << 20) + (256u << 10)); // 128 KB
  float*  Pp  = (float*) (ws + (9ull << 20));       // 16 MB [4][8192][128]
  float*  Dp  = (float*) (ws + (25ull << 20));      // 1 MB  [4][64][1024]

  prep_kernel<<<1216, 256, 0, stream>>>(x, Wq, Wk, Wv, Wo, W1, W2,
                                        xb, Wqt, Wkt, Wvt, Wot, W1t, W2t);
  proj_kernel<<<3072, 256, 0, stream>>>(xb, Wqt, Wkt, Wvt, Qb, Kb, Vt);
  attn_kernel<<<1024, 512, 0, stream>>>(Qb, Kb, Vt, e, Pp, Dp);
  fused_ffn_kernel<<<512, 512, 0, stream>>>(Pp, Dp, Wot, x, a1, W1t, b1,
                                            W2t, b2, a2, out);
}

// Round 10
// 173.221 us; speedup vs baseline: 1.1818x; 1.1818x over previous
//
#include <hip/hip_runtime.h>
#include <hip/hip_bf16.h>

// GATLayer: x[8,1024,128], e[8,1024,1024], H=8 dh=16, CLIP=10, FF=512.
// R10: 3 kernels. proj (f32 direct, on-the-fly bf16) -> attn (R6 structure,
// 2-trans Pade-tanh softmax, e/K/V prefetch, + Wo/W1/W2 transposes in
// prologue) -> fused ffn (unchanged R4).

typedef __attribute__((ext_vector_type(4)))  float  f32x4;
typedef __attribute__((ext_vector_type(16))) float  f32x16;
typedef __attribute__((ext_vector_type(8)))  __bf16 bf8v;

#define DEV static __device__ __forceinline__

DEV ushort f2bf(float f) {
  __hip_bfloat16 h = __float2bfloat16(f);
  return __builtin_bit_cast(ushort, h);
}

DEV uint cvtpk(float lo, float hi) {
  uint r;
  asm("v_cvt_pk_bf16_f32 %0, %1, %2" : "=v"(r) : "v"(lo), "v"(hi));
  return r;
}

DEV f32x16 zero16() {
  f32x16 z;
#pragma unroll
  for (int i = 0; i < 16; ++i) z[i] = 0.0f;
  return z;
}

union PU {
  uint u[4];
  bf8v v;
};

// D[n][k] = bf16(S[k][n]); one unit = 4 consecutive k.
DEV void tr_w(const float* __restrict__ S, ushort* __restrict__ D,
              int N, int K, int idx) {
  int kq = K >> 2;
  int n = idx / kq;
  int k = (idx - n * kq) << 2;
  ushort4 o;
  o.x = f2bf(S[(size_t)(k + 0) * N + n]);
  o.y = f2bf(S[(size_t)(k + 1) * N + n]);
  o.z = f2bf(S[(size_t)(k + 2) * N + n]);
  o.w = f2bf(S[(size_t)(k + 3) * N + n]);
  *(ushort4*)&D[(size_t)n * K + k] = o;
}

// ---------------- no-LDS 16x16x32 GEMM wave-tile (bf16 inputs) ------------
// A bf16 [M][K] row-major, Bt bf16 [N][K] row-major.
// A-frag: row=lane&15, k=8*(lane>>4)+j. C: col=lane&15, row=(lane>>4)*4+i.
template <int K>
DEV f32x4 gemm16(const ushort* __restrict__ A, const ushort* __restrict__ Bt,
                 int m0, int n0, int lane) {
  const int r = lane & 15, g = lane >> 4;
  const ushort* pa = A + (size_t)(m0 + r) * K + g * 8;
  const ushort* pb = Bt + (size_t)(n0 + r) * K + g * 8;
  f32x4 acc = {0.0f, 0.0f, 0.0f, 0.0f};
#pragma unroll
  for (int k0 = 0; k0 < K; k0 += 32) {
    bf8v a = *(const bf8v*)(pa + k0);
    bf8v b = *(const bf8v*)(pb + k0);
    acc = __builtin_amdgcn_mfma_f32_16x16x32_bf16(a, b, acc, 0, 0, 0);
  }
  return acc;
}

template <int K, int LDA>
DEV f32x4 gemm16_a_lds(const ushort* As, const ushort* __restrict__ Bt,
                       int n0, int lane) {
  const int r = lane & 15, g = lane >> 4;
  const ushort* pa = As + r * LDA + g * 8;
  const ushort* pb = Bt + (size_t)(n0 + r) * K + g * 8;
  f32x4 acc = {0.0f, 0.0f, 0.0f, 0.0f};
#pragma unroll
  for (int k0 = 0; k0 < K; k0 += 32) {
    bf8v a = *(const bf8v*)(pa + k0);
    bf8v b = *(const bf8v*)(pb + k0);
    acc = __builtin_amdgcn_mfma_f32_16x16x32_bf16(a, b, acc, 0, 0, 0);
  }
  return acc;
}

// ---------------- kernel 1: QKV projection, f32 inputs direct -------------
// 3 projs x 512 mt x 8 nt = 12288 wave-tiles; 4 waves/block -> 3072 blocks.
// Converts x and W tiles to bf16 in-register (no prep kernel, no xb buffer).
__global__ __launch_bounds__(256) void proj_kernel(
    const float* __restrict__ x,  const float* __restrict__ Wq,
    const float* __restrict__ Wk, const float* __restrict__ Wv,
    ushort* __restrict__ Qb, ushort* __restrict__ Kb, ushort* __restrict__ Vt) {
  const int w = blockIdx.x * 4 + (threadIdx.x >> 6);
  const int lane = threadIdx.x & 63;
  const int p = w >> 12;
  const int t = w & 4095;
  const int mt = t >> 3, nt = t & 7;
  const float* W = p == 0 ? Wq : (p == 1 ? Wk : Wv);
  const int r = lane & 15, g = lane >> 4;
  const float* pa = x + (size_t)(mt * 16 + r) * 128 + g * 8;
  const float* pb = W + (size_t)(g * 8) * 128 + nt * 16 + r;  // W[k][n]
  f32x4 acc = {0.0f, 0.0f, 0.0f, 0.0f};
#pragma unroll
  for (int k0 = 0; k0 < 128; k0 += 32) {
    f32x4 a0 = *(const f32x4*)(pa + k0);
    f32x4 a1 = *(const f32x4*)(pa + k0 + 4);
    float bb[8];
#pragma unroll
    for (int j = 0; j < 8; ++j) bb[j] = pb[(size_t)(k0 + j) * 128];
    PU af, bf_;
    af.u[0] = cvtpk(a0.x, a0.y);  af.u[1] = cvtpk(a0.z, a0.w);
    af.u[2] = cvtpk(a1.x, a1.y);  af.u[3] = cvtpk(a1.z, a1.w);
    bf_.u[0] = cvtpk(bb[0], bb[1]); bf_.u[1] = cvtpk(bb[2], bb[3]);
    bf_.u[2] = cvtpk(bb[4], bb[5]); bf_.u[3] = cvtpk(bb[6], bb[7]);
    acc = __builtin_amdgcn_mfma_f32_16x16x32_bf16(af.v, bf_.v, acc, 0, 0, 0);
  }
  const int col = lane & 15;
  const int h = nt, d = col;
  if (p < 2) {
    ushort* dst = p ? Kb : Qb;
#pragma unroll
    for (int i = 0; i < 4; ++i) {
      int m = mt * 16 + g * 4 + i;
      int bb2 = m >> 10, ns = m & 1023;
      dst[((size_t)(bb2 * 8 + h) * 1024 + ns) * 16 + d] = f2bf(acc[i]);
    }
  } else {
    int m0 = mt * 16 + g * 4;
    int bb2 = m0 >> 10, ns = m0 & 1023;
    ushort4 pk = make_ushort4(f2bf(acc[0]), f2bf(acc[1]),
                              f2bf(acc[2]), f2bf(acc[3]));
    *(ushort4*)&Vt[((size_t)(bb2 * 8 + h) * 16 + d) * 1024 + ns] = pk;
  }
}

// ---------------- kernel 2: fused attention -------------------------------
// grid = 256 (b, 32-q tile), 1024 thr = 16 waves = 8 heads x 2 m-halves.
// Swapped QK^T (32x32x16): lane owns q=lane&31. Softmax exponent via
// clamped Pade[2/2] tanh: E = C*y(945+105t+t^2)/(945+420t+15t^2) - C,
// t=y^2, C=10*log2(e); p = exp2(med3(E,-2C,0)).  2 trans/elem (rcp+exp2)
// vs 3 before. e/K/V prefetched one tile ahead. Prologue: first 36 blocks
// also transpose Wo/W1/W2 -> bf16 for the ffn kernel.
__global__ __launch_bounds__(1024, 4) void attn_kernel(
    const ushort* __restrict__ Qb, const ushort* __restrict__ Kb,
    const ushort* __restrict__ Vt, const float* __restrict__ e,
    ushort* __restrict__ AO,
    const float* __restrict__ Wo, const float* __restrict__ W1,
    const float* __restrict__ W2,
    ushort* __restrict__ Wot, ushort* __restrict__ W1t,
    ushort* __restrict__ W2t) {
  __shared__ float lacc[8][64][20];
  __shared__ float lsum[8][64];
  // prologue: weight transposes for ffn (36864 units over blocks 0..35)
  {
    int gi = blockIdx.x * 1024 + threadIdx.x;
    if      (gi < 4096)  tr_w(Wo, Wot, 128, 128, gi);
    else if (gi < 20480) tr_w(W1, W1t, 512, 128, gi - 4096);
    else if (gi < 36864) tr_w(W2, W2t, 128, 512, gi - 20480);
  }
  const int b = blockIdx.x >> 5, qt = blockIdx.x & 31;
  const int wv = threadIdx.x >> 6, lane = threadIdx.x & 63;
  const int h = wv & 7, mh = wv >> 3;
  const int lq = lane & 31, hi = lane >> 5;
  const int q0 = qt * 32;
  const ushort* Qh = Qb + (size_t)(b * 8 + h) * (1024 * 16);
  const ushort* Kh = Kb + (size_t)(b * 8 + h) * (1024 * 16);
  const ushort* Vh = Vt + (size_t)(b * 8 + h) * (16 * 1024);
  const float* erow = e + ((size_t)b * 1024 + q0 + lq) * 1024;

  const bf8v qf = *(const bf8v*)(Qh + (q0 + lq) * 16 + hi * 8);
  f32x16 acc = zero16();
  float ssum = 0.0f;
  const float C   = 14.4269504089f;    // 10*log2(e)
  const float NC  = -14.4269504089f;
  const float N2C = -28.8539008177f;

  const int mbase = mh * 512;
  // prefetch tile 0
  bf8v kf = *(const bf8v*)(Kh + (mbase + lq) * 16 + hi * 8);
  PU v0, v1;
#pragma unroll
  for (int j = 0; j < 4; ++j) { v0.u[j] = 0; v1.u[j] = 0; }
  if (lq < 16) {
    v0.v = *(const bf8v*)(Vh + lq * 1024 + mbase + hi * 8);
    v1.v = *(const bf8v*)(Vh + lq * 1024 + mbase + 16 + hi * 8);
  }
  f32x4 ev[4];
#pragma unroll
  for (int g = 0; g < 4; ++g)
    ev[g] = *(const f32x4*)(erow + mbase + 4 * hi + 8 * g);

  for (int mt = 0; mt < 16; ++mt) {
    // prefetch next tile
    bf8v kfn;
    PU v0n, v1n;
    f32x4 evn[4];
    if (mt < 15) {
      const int nb = mbase + (mt + 1) * 32;
      kfn = *(const bf8v*)(Kh + (nb + lq) * 16 + hi * 8);
#pragma unroll
      for (int j = 0; j < 4; ++j) { v0n.u[j] = 0; v1n.u[j] = 0; }
      if (lq < 16) {
        v0n.v = *(const bf8v*)(Vh + lq * 1024 + nb + hi * 8);
        v1n.v = *(const bf8v*)(Vh + lq * 1024 + nb + 16 + hi * 8);
      }
#pragma unroll
      for (int g = 0; g < 4; ++g)
        evn[g] = *(const f32x4*)(erow + nb + 4 * hi + 8 * g);
    }
    f32x16 s = __builtin_amdgcn_mfma_f32_32x32x16_bf16(kf, qf, zero16(), 0, 0, 0);
    float p[16];
#pragma unroll
    for (int r = 0; r < 16; ++r) {
      float y = fmaf(s[r], 0.25f, ev[r >> 2][r & 3]);
      float tt = y * y;
      // C*num = y*(C*945 + C*105*t + C*t^2)
      float num = y * fmaf(tt, fmaf(tt, C, 1514.82979f), 13633.4681f);
      float den = fmaf(tt, fmaf(tt, 15.0f, 420.0f), 945.0f);
      float E = fmaf(num, __builtin_amdgcn_rcpf(den), NC);
      E = __builtin_amdgcn_fmed3f(E, N2C, 0.0f);
      float pp = __builtin_amdgcn_exp2f(E);
      p[r] = pp;
      ssum += pp;
    }
    uint w[8];
#pragma unroll
    for (int j = 0; j < 8; ++j) w[j] = cvtpk(p[2 * j], p[2 * j + 1]);
    asm("v_permlane32_swap_b32 %0, %1" : "+v"(w[0]), "+v"(w[2]));
    asm("v_permlane32_swap_b32 %0, %1" : "+v"(w[1]), "+v"(w[3]));
    asm("v_permlane32_swap_b32 %0, %1" : "+v"(w[4]), "+v"(w[6]));
    asm("v_permlane32_swap_b32 %0, %1" : "+v"(w[5]), "+v"(w[7]));
    PU a0, a1;
    a0.u[0] = w[0]; a0.u[1] = w[1]; a0.u[2] = w[2]; a0.u[3] = w[3];
    a1.u[0] = w[4]; a1.u[1] = w[5]; a1.u[2] = w[6]; a1.u[3] = w[7];
    acc = __builtin_amdgcn_mfma_f32_32x32x16_bf16(a0.v, v0.v, acc, 0, 0, 0);
    acc = __builtin_amdgcn_mfma_f32_32x32x16_bf16(a1.v, v1.v, acc, 0, 0, 0);
    if (mt < 15) {
      kf = kfn; v0 = v0n; v1 = v1n;
#pragma unroll
      for (int g = 0; g < 4; ++g) ev[g] = evn[g];
    }
  }

  if (mh) {
#pragma unroll
    for (int r = 0; r < 16; ++r) lacc[h][lane][r] = acc[r];
    lsum[h][lane] = ssum;
  }
  __syncthreads();
  if (!mh) {
#pragma unroll
    for (int r = 0; r < 16; ++r) acc[r] += lacc[h][lane][r];
    ssum += lsum[h][lane];
    float tot = ssum + __shfl_xor(ssum, 32);
#pragma unroll
    for (int r = 0; r < 16; ++r) {
      int qr = (r & 3) + 8 * (r >> 2) + 4 * hi;
      float dn = __shfl(tot, qr);
      if (lq < 16) {
        float o = acc[r] * __builtin_amdgcn_rcpf(dn);
        AO[((size_t)(b * 1024) + q0 + qr) * 128 + h * 16 + lq] = f2bf(o);
      }
    }
  }
}

// ---------------- kernel 3: Wo+res1 -> FFN1(relu) -> FFN2+res2 ------------
// grid = 512 blocks (one per 16-row m-tile), 512 thr = 8 waves.
__global__ __launch_bounds__(512) void fused_ffn_kernel(
    const ushort* __restrict__ AO, const ushort* __restrict__ Wot,
    const float* __restrict__ x, const float* __restrict__ alpha1,
    const ushort* __restrict__ W1t, const float* __restrict__ b1,
    const ushort* __restrict__ W2t, const float* __restrict__ b2,
    const float* __restrict__ alpha2, float* __restrict__ out) {
  __shared__ float  X1f[16][132];
  __shared__ ushort X1b[16][136];
  __shared__ ushort Hs[16][520];
  const int mt = blockIdx.x;
  const int w = threadIdx.x >> 6, lane = threadIdx.x & 63;
  const int g = lane >> 4, col = lane & 15;
  const float a1 = *alpha1, a2 = *alpha2;

  {
    f32x4 acc = gemm16<128>(AO, Wot, mt * 16, w * 16, lane);
    int n = w * 16 + col;
#pragma unroll
    for (int i = 0; i < 4; ++i) {
      int row = g * 4 + i;
      float v = x[(size_t)(mt * 16 + row) * 128 + n] + a1 * acc[i];
      X1f[row][n] = v;
      X1b[row][n] = f2bf(v);
    }
  }
  __syncthreads();

#pragma unroll
  for (int j = 0; j < 4; ++j) {
    int n0 = w * 64 + j * 16;
    f32x4 acc = gemm16_a_lds<128, 136>(&X1b[0][0], W1t, n0, lane);
    int n = n0 + col;
    float bias = b1[n];
#pragma unroll
    for (int i = 0; i < 4; ++i) {
      int row = g * 4 + i;
      Hs[row][n] = f2bf(fmaxf(acc[i] + bias, 0.0f));
    }
  }
  __syncthreads();

  {
    f32x4 acc = gemm16_a_lds<512, 520>(&Hs[0][0], W2t, w * 16, lane);
    int n = w * 16 + col;
    float bias = b2[n];
#pragma unroll
    for (int i = 0; i < 4; ++i) {
      int row = g * 4 + i;
      out[(size_t)(mt * 16 + row) * 128 + n] =
          X1f[row][n] + a2 * (acc[i] + bias);
    }
  }
}

// ---------------- launcher -------------------------------------------------
extern "C" void kernel_launch(void* const* d_in, const int* in_sizes, int n_in,
                              void* d_out, int out_size, void* d_ws, size_t ws_size,
                              hipStream_t stream) {
  (void)in_sizes; (void)n_in; (void)out_size; (void)ws_size;
  const float* x  = (const float*)d_in[0];
  const float* e  = (const float*)d_in[1];
  const float* Wq = (const float*)d_in[2];
  const float* Wk = (const float*)d_in[3];
  const float* Wv = (const float*)d_in[4];
  const float* Wo = (const float*)d_in[5];
  const float* W1 = (const float*)d_in[6];
  const float* b1 = (const float*)d_in[7];
  const float* W2 = (const float*)d_in[8];
  const float* b2 = (const float*)d_in[9];
  const float* a1 = (const float*)d_in[10];
  const float* a2 = (const float*)d_in[11];
  float* out = (float*)d_out;

  char* ws = (char*)d_ws;
  ushort* Qb  = (ushort*)(ws);                      // 2 MB [B,H,N,16]
  ushort* Kb  = (ushort*)(ws + (2ull << 20));       // 2 MB
  ushort* Vt  = (ushort*)(ws + (4ull << 20));       // 2 MB [B,H,16,N]
  ushort* AO  = (ushort*)(ws + (6ull << 20));       // 2 MB [8192,128]
  ushort* Wot = (ushort*)(ws + (8ull << 20));               // 32 KB
  ushort* W1t = (ushort*)(ws + (8ull << 20) + (64u << 10)); // 128 KB
  ushort* W2t = (ushort*)(ws + (8ull << 20) + (192u << 10));// 128 KB

  proj_kernel<<<3072, 256, 0, stream>>>(x, Wq, Wk, Wv, Qb, Kb, Vt);
  attn_kernel<<<256, 1024, 0, stream>>>(Qb, Kb, Vt, e, AO,
                                        Wo, W1, W2, Wot, W1t, W2t);
  fused_ffn_kernel<<<512, 512, 0, stream>>>(AO, Wot, x, a1, W1t, b1,
                                            W2t, b2, a2, out);
}

// Round 12
// 167.213 us; speedup vs baseline: 1.2242x; 1.0359x over previous
//
#include <hip/hip_runtime.h>
#include <hip/hip_bf16.h>

// GATLayer: x[8,1024,128], e[8,1024,1024], H=8 dh=16, CLIP=10, FF=512.
// R11: 2 kernels. proj (f32 direct + weight transposes in extra blocks) ->
// merged attn+Wo+res1+FFN1+FFN2+res2 (one block owns a full 32-row tile:
// all 8 heads -> AO tile in LDS -> ffn chain in-block, X1 in registers).

typedef __attribute__((ext_vector_type(4)))  float  f32x4;
typedef __attribute__((ext_vector_type(16))) float  f32x16;
typedef __attribute__((ext_vector_type(8)))  __bf16 bf8v;

#define DEV static __device__ __forceinline__

DEV ushort f2bf(float f) {
  __hip_bfloat16 h = __float2bfloat16(f);
  return __builtin_bit_cast(ushort, h);
}

DEV uint cvtpk(float lo, float hi) {
  uint r;
  asm("v_cvt_pk_bf16_f32 %0, %1, %2" : "=v"(r) : "v"(lo), "v"(hi));
  return r;
}

DEV f32x16 zero16() {
  f32x16 z;
#pragma unroll
  for (int i = 0; i < 16; ++i) z[i] = 0.0f;
  return z;
}

union PU {
  uint u[4];
  bf8v v;
};

// D[n][k] = bf16(S[k][n]); one unit = 4 consecutive k.
DEV void tr_w(const float* __restrict__ S, ushort* __restrict__ D,
              int N, int K, int idx) {
  int kq = K >> 2;
  int n = idx / kq;
  int k = (idx - n * kq) << 2;
  ushort4 o;
  o.x = f2bf(S[(size_t)(k + 0) * N + n]);
  o.y = f2bf(S[(size_t)(k + 1) * N + n]);
  o.z = f2bf(S[(size_t)(k + 2) * N + n]);
  o.w = f2bf(S[(size_t)(k + 3) * N + n]);
  *(ushort4*)&D[(size_t)n * K + k] = o;
}

// 16x16x32 wave-tile GEMM, A from LDS (row stride LDA ushorts), Bt global.
// A-frag: row=lane&15, k=8*(lane>>4)+j. C: col=lane&15, row=(lane>>4)*4+i.
template <int K, int LDA>
DEV f32x4 gemm16_a_lds(const ushort* As, const ushort* __restrict__ Bt,
                       int n0, int lane) {
  const int r = lane & 15, g = lane >> 4;
  const ushort* pa = As + r * LDA + g * 8;
  const ushort* pb = Bt + (size_t)(n0 + r) * K + g * 8;
  f32x4 acc = {0.0f, 0.0f, 0.0f, 0.0f};
#pragma unroll
  for (int k0 = 0; k0 < K; k0 += 32) {
    bf8v a = *(const bf8v*)(pa + k0);
    bf8v b = *(const bf8v*)(pb + k0);
    acc = __builtin_amdgcn_mfma_f32_16x16x32_bf16(a, b, acc, 0, 0, 0);
  }
  return acc;
}

// ---------------- kernel 1: QKV projection + weight transposes ------------
// blocks 0..3071: 3 projs x 512 mt x 8 nt wave-tiles, f32 inputs direct.
// blocks 3072..3215: transpose Wo/W1/W2 -> bf16 [n][k] for the ffn phase.
__global__ __launch_bounds__(256) void proj_kernel(
    const float* __restrict__ x,  const float* __restrict__ Wq,
    const float* __restrict__ Wk, const float* __restrict__ Wv,
    const float* __restrict__ Wo, const float* __restrict__ W1,
    const float* __restrict__ W2,
    ushort* __restrict__ Qb, ushort* __restrict__ Kb, ushort* __restrict__ Vt,
    ushort* __restrict__ Wot, ushort* __restrict__ W1t,
    ushort* __restrict__ W2t) {
  const int bid = blockIdx.x;
  if (bid >= 3072) {
    int gi = (bid - 3072) * 256 + threadIdx.x;   // 36864 units
    if      (gi < 4096)  tr_w(Wo, Wot, 128, 128, gi);
    else if (gi < 20480) tr_w(W1, W1t, 512, 128, gi - 4096);
    else                 tr_w(W2, W2t, 128, 512, gi - 20480);
    return;
  }
  const int w = bid * 4 + (threadIdx.x >> 6);
  const int lane = threadIdx.x & 63;
  const int p = w >> 12;
  const int t = w & 4095;
  const int mt = t >> 3, nt = t & 7;
  const float* W = p == 0 ? Wq : (p == 1 ? Wk : Wv);
  const int r = lane & 15, g = lane >> 4;
  const float* pa = x + (size_t)(mt * 16 + r) * 128 + g * 8;
  const float* pb = W + (size_t)(g * 8) * 128 + nt * 16 + r;  // W[k][n]
  f32x4 acc = {0.0f, 0.0f, 0.0f, 0.0f};
#pragma unroll
  for (int k0 = 0; k0 < 128; k0 += 32) {
    f32x4 a0 = *(const f32x4*)(pa + k0);
    f32x4 a1 = *(const f32x4*)(pa + k0 + 4);
    float bb[8];
#pragma unroll
    for (int j = 0; j < 8; ++j) bb[j] = pb[(size_t)(k0 + j) * 128];
    PU af, bf_;
    af.u[0] = cvtpk(a0.x, a0.y);  af.u[1] = cvtpk(a0.z, a0.w);
    af.u[2] = cvtpk(a1.x, a1.y);  af.u[3] = cvtpk(a1.z, a1.w);
    bf_.u[0] = cvtpk(bb[0], bb[1]); bf_.u[1] = cvtpk(bb[2], bb[3]);
    bf_.u[2] = cvtpk(bb[4], bb[5]); bf_.u[3] = cvtpk(bb[6], bb[7]);
    acc = __builtin_amdgcn_mfma_f32_16x16x32_bf16(af.v, bf_.v, acc, 0, 0, 0);
  }
  const int col = lane & 15;
  const int h = nt, d = col;
  if (p < 2) {
    ushort* dst = p ? Kb : Qb;
#pragma unroll
    for (int i = 0; i < 4; ++i) {
      int m = mt * 16 + g * 4 + i;
      int bb2 = m >> 10, ns = m & 1023;
      dst[((size_t)(bb2 * 8 + h) * 1024 + ns) * 16 + d] = f2bf(acc[i]);
    }
  } else {
    int m0 = mt * 16 + g * 4;
    int bb2 = m0 >> 10, ns = m0 & 1023;
    ushort4 pk = make_ushort4(f2bf(acc[0]), f2bf(acc[1]),
                              f2bf(acc[2]), f2bf(acc[3]));
    *(ushort4*)&Vt[((size_t)(bb2 * 8 + h) * 16 + d) * 1024 + ns] = pk;
  }
}

// ---------------- kernel 2: attention + Wo + res1 + FFN1 + FFN2 + res2 ----
// grid = 256 (b, 32-q tile), 1024 thr = 16 waves = 8 heads x 2 m-halves.
// Attn: swapped QK^T 32x32x16, lane owns q=lane&31; tanh clip -> fixed-max
// softmax exp2(C1/(1+exp2(C2*y))); permlane32_swap pack; LDS combine ->
// normalized AO tile (32x128 bf16) in LDS -> stepW/ffn1/ffn2 in-block.
// X1 kept in f32 registers (stepW wave/lane C-tile == ffn2 wave/lane C-tile).
// LDS overlay: [lacc+lsum 43K | Hs 33.3K] + AOs 8.5K + X1b 8.5K = 59K.
__global__ __launch_bounds__(1024, 4) void attn_ffn_kernel(
    const ushort* __restrict__ Qb, const ushort* __restrict__ Kb,
    const ushort* __restrict__ Vt, const float* __restrict__ e,
    const float* __restrict__ x, const float* __restrict__ alpha1,
    const ushort* __restrict__ Wot, const ushort* __restrict__ W1t,
    const float* __restrict__ b1, const ushort* __restrict__ W2t,
    const float* __restrict__ b2, const float* __restrict__ alpha2,
    float* __restrict__ out) {
  __shared__ __align__(16) char smem[60416];
  float (*lacc)[64][20] = (float (*)[64][20])smem;            // [8][64][20] f32
  float (*lsum)[64]     = (float (*)[64])(smem + 40960);      // [8][64] f32
  ushort (*Hs)[520]     = (ushort (*)[520])smem;              // [32][520] (overlay)
  ushort (*AOs)[136]    = (ushort (*)[136])(smem + 43008);    // [32][136]
  ushort (*X1b)[136]    = (ushort (*)[136])(smem + 51712);    // [32][136]

  const int b = blockIdx.x >> 5, qt = blockIdx.x & 31;
  const int wv = threadIdx.x >> 6, lane = threadIdx.x & 63;
  const int h = wv & 7, mh = wv >> 3;
  const int lq = lane & 31, hi = lane >> 5;
  const int q0 = qt * 32;
  const ushort* Qh = Qb + (size_t)(b * 8 + h) * (1024 * 16);
  const ushort* Kh = Kb + (size_t)(b * 8 + h) * (1024 * 16);
  const ushort* Vh = Vt + (size_t)(b * 8 + h) * (16 * 1024);
  const float* erow = e + ((size_t)b * 1024 + q0 + lq) * 1024;

  const bf8v qf = *(const bf8v*)(Qh + (q0 + lq) * 16 + hi * 8);
  f32x16 acc = zero16();
  float ssum = 0.0f;
  const float C2 = 2.8853900817779268f;    // 2*log2(e)
  const float C1 = -28.853900817779268f;   // -20*log2(e)

#pragma unroll 2
  for (int mt = 0; mt < 16; ++mt) {
    const int mbase = mh * 512 + mt * 32;
    bf8v kf = *(const bf8v*)(Kh + (mbase + lq) * 16 + hi * 8);
    f32x16 s = __builtin_amdgcn_mfma_f32_32x32x16_bf16(kf, qf, zero16(), 0, 0, 0);
    f32x4 ev[4];
#pragma unroll
    for (int g = 0; g < 4; ++g)
      ev[g] = *(const f32x4*)(erow + mbase + 4 * hi + 8 * g);
    float p[16];
#pragma unroll
    for (int r = 0; r < 16; ++r) {
      float y = fmaf(s[r], 0.25f, ev[r >> 2][r & 3]);
      // p = exp(10*tanh(y) - 10) = exp2(C1 / (1 + exp2(C2*y)))
      float z = __builtin_amdgcn_exp2f(C2 * y);
      float pp = __builtin_amdgcn_exp2f(C1 * __builtin_amdgcn_rcpf(1.0f + z));
      p[r] = pp;
      ssum += pp;
    }
    uint w[8];
#pragma unroll
    for (int j = 0; j < 8; ++j) w[j] = cvtpk(p[2 * j], p[2 * j + 1]);
    asm("v_permlane32_swap_b32 %0, %1" : "+v"(w[0]), "+v"(w[2]));
    asm("v_permlane32_swap_b32 %0, %1" : "+v"(w[1]), "+v"(w[3]));
    asm("v_permlane32_swap_b32 %0, %1" : "+v"(w[4]), "+v"(w[6]));
    asm("v_permlane32_swap_b32 %0, %1" : "+v"(w[5]), "+v"(w[7]));
    PU a0, a1;
    a0.u[0] = w[0]; a0.u[1] = w[1]; a0.u[2] = w[2]; a0.u[3] = w[3];
    a1.u[0] = w[4]; a1.u[1] = w[5]; a1.u[2] = w[6]; a1.u[3] = w[7];
    PU v0, v1;
#pragma unroll
    for (int j = 0; j < 4; ++j) { v0.u[j] = 0; v1.u[j] = 0; }
    if (lq < 16) {
      v0.v = *(const bf8v*)(Vh + lq * 1024 + mbase + hi * 8);
      v1.v = *(const bf8v*)(Vh + lq * 1024 + mbase + 16 + hi * 8);
    }
    acc = __builtin_amdgcn_mfma_f32_32x32x16_bf16(a0.v, v0.v, acc, 0, 0, 0);
    acc = __builtin_amdgcn_mfma_f32_32x32x16_bf16(a1.v, v1.v, acc, 0, 0, 0);
  }

  // combine m-halves; normalized AO tile -> LDS (bf16)
  if (mh) {
#pragma unroll
    for (int r = 0; r < 16; ++r) lacc[h][lane][r] = acc[r];
    lsum[h][lane] = ssum;
  }
  __syncthreads();
  if (!mh) {
#pragma unroll
    for (int r = 0; r < 16; ++r) acc[r] += lacc[h][lane][r];
    ssum += lsum[h][lane];
    float tot = ssum + __shfl_xor(ssum, 32);
#pragma unroll
    for (int r = 0; r < 16; ++r) {
      int qr = (r & 3) + 8 * (r >> 2) + 4 * hi;
      float dn = __shfl(tot, qr);
      if (lq < 16)
        AOs[qr][h * 16 + lq] = f2bf(acc[r] * __builtin_amdgcn_rcpf(dn));
    }
  }
  __syncthreads();

  // step W: X1 = x + a1*(AO @ Wo); wave (rh, wh) owns 16x16 tile
  const int rh = mh, wh = h;            // same decomposition, renamed
  const int g = lane >> 4, col = lane & 15;
  const float a1v = *alpha1;
  f32x4 X1r;
  {
    f32x4 a4 = gemm16_a_lds<128, 136>(&AOs[rh * 16][0], Wot, wh * 16, lane);
    int n = wh * 16 + col;
#pragma unroll
    for (int i = 0; i < 4; ++i) {
      int row = rh * 16 + g * 4 + i;
      int m = b * 1024 + q0 + row;
      float v = x[(size_t)m * 128 + n] + a1v * a4[i];
      X1r[i] = v;
      X1b[row][n] = f2bf(v);
    }
  }
  __syncthreads();

  // ffn1: H = relu(X1b @ W1 + b1); wave covers 4 n-tiles of its row-half
#pragma unroll
  for (int j = 0; j < 4; ++j) {
    int n0 = (wh * 4 + j) * 16;
    f32x4 a4 = gemm16_a_lds<128, 136>(&X1b[rh * 16][0], W1t, n0, lane);
    int n = n0 + col;
    float bias = b1[n];
#pragma unroll
    for (int i = 0; i < 4; ++i)
      Hs[rh * 16 + g * 4 + i][n] = f2bf(fmaxf(a4[i] + bias, 0.0f));
  }
  __syncthreads();

  // ffn2: out = X1 + a2*(H @ W2 + b2); same (rh, wh) tile as step W
  {
    const float a2v = *alpha2;
    f32x4 a4 = gemm16_a_lds<512, 520>(&Hs[rh * 16][0], W2t, wh * 16, lane);
    int n = wh * 16 + col;
    float bias = b2[n];
#pragma unroll
    for (int i = 0; i < 4; ++i) {
      int m = b * 1024 + q0 + rh * 16 + g * 4 + i;
      out[(size_t)m * 128 + n] = X1r[i] + a2v * (a4[i] + bias);
    }
  }
}

// ---------------- launcher -------------------------------------------------
extern "C" void kernel_launch(void* const* d_in, const int* in_sizes, int n_in,
                              void* d_out, int out_size, void* d_ws, size_t ws_size,
                              hipStream_t stream) {
  (void)in_sizes; (void)n_in; (void)out_size; (void)ws_size;
  const float* x  = (const float*)d_in[0];
  const float* e  = (const float*)d_in[1];
  const float* Wq = (const float*)d_in[2];
  const float* Wk = (const float*)d_in[3];
  const float* Wv = (const float*)d_in[4];
  const float* Wo = (const float*)d_in[5];
  const float* W1 = (const float*)d_in[6];
  const float* b1 = (const float*)d_in[7];
  const float* W2 = (const float*)d_in[8];
  const float* b2 = (const float*)d_in[9];
  const float* a1 = (const float*)d_in[10];
  const float* a2 = (const float*)d_in[11];
  float* out = (float*)d_out;

  char* ws = (char*)d_ws;
  ushort* Qb  = (ushort*)(ws);                      // 2 MB [B,H,N,16]
  ushort* Kb  = (ushort*)(ws + (2ull << 20));       // 2 MB
  ushort* Vt  = (ushort*)(ws + (4ull << 20));       // 2 MB [B,H,16,N]
  ushort* Wot = (ushort*)(ws + (6ull << 20));               // 32 KB
  ushort* W1t = (ushort*)(ws + (6ull << 20) + (64u << 10)); // 128 KB
  ushort* W2t = (ushort*)(ws + (6ull << 20) + (192u << 10));// 128 KB

  proj_kernel<<<3216, 256, 0, stream>>>(x, Wq, Wk, Wv, Wo, W1, W2,
                                        Qb, Kb, Vt, Wot, W1t, W2t);
  attn_ffn_kernel<<<256, 1024, 0, stream>>>(Qb, Kb, Vt, e, x, a1,
                                            Wot, W1t, b1, W2t, b2, a2, out);
}